// Round 1
// baseline (5740.091 us; speedup 1.0000x reference)
//
#include <hip/hip_runtime.h>
#include <cstdint>
#include <cstddef>

// Model dims
#define T_ 256
#define B_ 128
#define D_ 128
#define H_ 1024
#define K1_ 1152   // D + H
#define K2_ 2048   // 2H

typedef __bf16 bf16x8 __attribute__((ext_vector_type(8)));
typedef short s8 __attribute__((ext_vector_type(8)));
typedef float f32x4 __attribute__((ext_vector_type(4)));

__device__ __forceinline__ unsigned short f2bf(float f) {
  unsigned int u = __builtin_bit_cast(unsigned int, f);
  u += 0x7fff + ((u >> 16) & 1);   // RNE
  return (unsigned short)(u >> 16);
}
__device__ __forceinline__ float sigm(float x) { return 1.f / (1.f + __expf(-x)); }
__device__ __forceinline__ float tanh_(float x) { return 1.f - 2.f / (__expf(2.f * x) + 1.f); }

__device__ __forceinline__ f32x4 mfma16(s8 a, s8 b, f32x4 c) {
  return __builtin_amdgcn_mfma_f32_16x16x32_bf16(
      __builtin_bit_cast(bf16x8, a), __builtin_bit_cast(bf16x8, b), c, 0, 0, 0);
}

// ---------------------------------------------------------------------------
// Prep: convert inSeq -> bf16, pack outW -> [col][k] bf16, zero states/loss
// ---------------------------------------------------------------------------
__global__ void prep_misc(const float* __restrict__ inSeq,
                          const float* __restrict__ outW,
                          unsigned short* __restrict__ xbf,
                          unsigned short* __restrict__ outWp,
                          unsigned short* __restrict__ h1b,
                          unsigned short* __restrict__ h2all,
                          float* __restrict__ c1, float* __restrict__ c2,
                          float* __restrict__ loss)
{
  int i = blockIdx.x * 256 + threadIdx.x;
  if (i < T_ * B_ * D_) xbf[i] = f2bf(inSeq[i]);
  if (i < B_ * H_) {
    c1[i] = 0.f; c2[i] = 0.f;
    h1b[B_ * H_ + i] = 0;     // h1 parity-1 buffer (read at phase 0) = 0
    h2all[i] = 0;             // slot 0 = h2(t=-1) = 0
  }
  if (i < H_ * D_) {          // outWp[c][k] = outW[k][c]
    int c = i >> 10, k = i & 1023;
    outWp[i] = f2bf(outW[(size_t)k * D_ + c]);
  }
  if (i == 0) loss[0] = 0.f;
}

// ---------------------------------------------------------------------------
// Pack LSTM weights: src fp32 [K][4096] (gate-major cols: i|j|f|o blocks of H)
//   -> dst bf16 [4096][K], dst row = 4*j + g  (gate-interleaved, k-major)
// grid: (K/64, 16, 4), 256 threads
// ---------------------------------------------------------------------------
__global__ void pack_w(const float* __restrict__ src, unsigned short* __restrict__ dst, int K)
{
  __shared__ float tile[64][65];
  int k0 = blockIdx.x * 64, j0 = blockIdx.y * 64, g = blockIdx.z;
  int tid = threadIdx.x;
#pragma unroll
  for (int e = 0; e < 16; ++e) {
    int li = e * 256 + tid;
    int kl = li >> 6, jl = li & 63;
    tile[kl][jl] = src[(size_t)(k0 + kl) * 4096 + g * 1024 + j0 + jl];
  }
  __syncthreads();
#pragma unroll
  for (int e = 0; e < 16; ++e) {
    int li = e * 256 + tid;
    int jl = li >> 6, kl = li & 63;
    dst[(size_t)((j0 + jl) * 4 + g) * K + k0 + kl] = f2bf(tile[kl][jl]);
  }
}

// ---------------------------------------------------------------------------
// Phase kernel: phase p runs L1(t=p) on blocks 0..255 and L2(t=p-1) on
// blocks 256..511. Each block: 64-row x 32-col z-tile, K split over 4 waves,
// LDS reduction, fused LSTM epilogue (gates interleaved in packed W cols).
// ---------------------------------------------------------------------------
__global__ __launch_bounds__(256, 2) void phase_kernel(
    int p,
    const unsigned short* __restrict__ xbf,
    const unsigned short* __restrict__ W1p,
    const unsigned short* __restrict__ W2p,
    const float* __restrict__ b1,
    const float* __restrict__ b2,
    unsigned short* __restrict__ h1b,
    unsigned short* __restrict__ h2all,
    float* __restrict__ c1,
    float* __restrict__ c2)
{
  __shared__ float red[4][2048];   // 4 wave partials of 64x32 fp32
  const int bid = blockIdx.x;
  const bool isL2 = bid >= 256;
  if (!isL2 && p >= T_) return;
  if (isL2 && p == 0) return;
  const int jb = isL2 ? (bid - 256) : bid;
  const int mt = jb & 1, nt = jb >> 1;      // 2 M-tiles x 128 N-tiles
  const int t = isL2 ? (p - 1) : p;
  const int r0 = mt * 64, c0 = nt * 32;
  const int tid = threadIdx.x;
  const int wid = tid >> 6, lane = tid & 63;
  const int quad = lane >> 4, l15 = lane & 15;
  const int kseg = quad * 8;

  // h1 produced at phase p-1 lives in parity (p-1)&1 == (p+1)&1
  const unsigned short* hsrc = h1b + (size_t)((p + 1) & 1) * (B_ * H_);

  f32x4 acc[4][2];
#pragma unroll
  for (int i = 0; i < 4; ++i)
#pragma unroll
    for (int j = 0; j < 2; ++j) acc[i][j] = (f32x4){0.f, 0.f, 0.f, 0.f};

  int arow[4], bcol[2];
#pragma unroll
  for (int i = 0; i < 4; ++i) arow[i] = r0 + i * 16 + l15;
#pragma unroll
  for (int j = 0; j < 2; ++j) bcol[j] = c0 + j * 16 + l15;

  if (!isL2) {
    // ----- layer 1: A = [x_t | h1(t-1)], K = 1152 -----
    const unsigned short* xt = xbf + (size_t)t * (B_ * D_);
    const int cpw = 9;                 // 36 chunks / 4 waves
    const int kcbase = wid * cpw;
    s8 a[4], b[2], an[4], bn[2];
    auto LD = [&](int kc, s8* A, s8* Bv) {
      int kk = kc * 32 + kseg;
      if (kk < D_) {
#pragma unroll
        for (int i = 0; i < 4; ++i) A[i] = *(const s8*)(xt + (size_t)arow[i] * D_ + kk);
      } else {
#pragma unroll
        for (int i = 0; i < 4; ++i) A[i] = *(const s8*)(hsrc + (size_t)arow[i] * H_ + (kk - D_));
      }
#pragma unroll
      for (int j = 0; j < 2; ++j) Bv[j] = *(const s8*)(W1p + (size_t)bcol[j] * K1_ + kk);
    };
    LD(kcbase, a, b);
    for (int c = 0; c < cpw; ++c) {
      if (c + 1 < cpw) LD(kcbase + c + 1, an, bn);
#pragma unroll
      for (int i = 0; i < 4; ++i)
#pragma unroll
        for (int j = 0; j < 2; ++j) acc[i][j] = mfma16(a[i], b[j], acc[i][j]);
#pragma unroll
      for (int i = 0; i < 4; ++i) a[i] = an[i];
      b[0] = bn[0]; b[1] = bn[1];
    }
  } else {
    // ----- layer 2: A = [h1(t) | h2(t-1)], K = 2048 -----
    const unsigned short* h2prev = h2all + (size_t)t * (B_ * H_);   // slot t = h2(t-1)
    const int cpw = 16;                // 64 chunks / 4 waves
    const int kcbase = wid * cpw;
    s8 a[4], b[2], an[4], bn[2];
    auto LD = [&](int kc, s8* A, s8* Bv) {
      int kk = kc * 32 + kseg;
      if (kk < H_) {
#pragma unroll
        for (int i = 0; i < 4; ++i) A[i] = *(const s8*)(hsrc + (size_t)arow[i] * H_ + kk);
      } else {
#pragma unroll
        for (int i = 0; i < 4; ++i) A[i] = *(const s8*)(h2prev + (size_t)arow[i] * H_ + (kk - H_));
      }
#pragma unroll
      for (int j = 0; j < 2; ++j) Bv[j] = *(const s8*)(W2p + (size_t)bcol[j] * K2_ + kk);
    };
    LD(kcbase, a, b);
    for (int c = 0; c < cpw; ++c) {
      if (c + 1 < cpw) LD(kcbase + c + 1, an, bn);
#pragma unroll
      for (int i = 0; i < 4; ++i)
#pragma unroll
        for (int j = 0; j < 2; ++j) acc[i][j] = mfma16(a[i], b[j], acc[i][j]);
#pragma unroll
      for (int i = 0; i < 4; ++i) a[i] = an[i];
      b[0] = bn[0]; b[1] = bn[1];
    }
  }

  // ----- reduce 4 wave partials -----
#pragma unroll
  for (int i = 0; i < 4; ++i)
#pragma unroll
    for (int j = 0; j < 2; ++j)
#pragma unroll
      for (int r = 0; r < 4; ++r)
        red[wid][(i * 16 + quad * 4 + r) * 32 + (j * 16 + l15)] = acc[i][j][r];
  __syncthreads();
#pragma unroll
  for (int it = 0; it < 8; ++it) {
    int e = it * 256 + tid;
    red[0][e] = red[0][e] + red[1][e] + red[2][e] + red[3][e];
  }
  __syncthreads();

  // ----- fused LSTM epilogue: 64 rows x 8 h-units (gates interleaved) -----
  const float* bias = isL2 ? b2 : b1;
  float* cst = isL2 ? c2 : c1;
  unsigned short* hout = isL2 ? (h2all + (size_t)(t + 1) * (B_ * H_))
                              : (h1b + (size_t)(p & 1) * (B_ * H_));
#pragma unroll
  for (int it = 0; it < 2; ++it) {
    int s = it * 256 + tid;
    int row = s >> 3, u = s & 7;
    int jg = (c0 >> 2) + u;            // global h-unit
    float zi = red[0][row * 32 + u * 4 + 0] + bias[0 * H_ + jg];
    float zj = red[0][row * 32 + u * 4 + 1] + bias[1 * H_ + jg];
    float zf = red[0][row * 32 + u * 4 + 2] + bias[2 * H_ + jg];
    float zo = red[0][row * 32 + u * 4 + 3] + bias[3 * H_ + jg];
    int rg = r0 + row;
    float co = cst[(size_t)rg * H_ + jg];
    float cn = co * sigm(zf + 1.0f) + sigm(zi) * tanh_(zj);
    float hn = tanh_(cn) * sigm(zo);
    cst[(size_t)rg * H_ + jg] = cn;
    hout[(size_t)rg * H_ + jg] = f2bf(hn);
  }
}

// ---------------------------------------------------------------------------
// Tail: logits = h2 @ outW + outB, dual softmax, probs out, CE loss.
// One block per 128 rows; 128x128x1024 GEMM; logits staged in LDS.
// ---------------------------------------------------------------------------
__global__ __launch_bounds__(256, 1) void proj_kernel(
    const unsigned short* __restrict__ h2flat,   // h2all + B*H (slots 1..256)
    const unsigned short* __restrict__ outWp,    // [col][k] bf16
    const float* __restrict__ outB,
    const int* __restrict__ targets,
    float* __restrict__ out,
    float* __restrict__ loss)
{
  __shared__ float lg[128][129];
  __shared__ float red2[256];
  const int r0 = blockIdx.x * 128;
  const int tid = threadIdx.x;
  const int wid = tid >> 6, lane = tid & 63;
  const int quad = lane >> 4, l15 = lane & 15;
  const int wr = (wid & 1) * 64, wc = (wid >> 1) * 64;
  const int kseg = quad * 8;

  f32x4 acc[4][4];
#pragma unroll
  for (int i = 0; i < 4; ++i)
#pragma unroll
    for (int j = 0; j < 4; ++j) acc[i][j] = (f32x4){0.f, 0.f, 0.f, 0.f};

  int arow[4], bcolv[4];
#pragma unroll
  for (int i = 0; i < 4; ++i) arow[i] = r0 + wr + i * 16 + l15;
#pragma unroll
  for (int j = 0; j < 4; ++j) bcolv[j] = wc + j * 16 + l15;

  s8 a[4], b[4], an[4], bn[4];
  auto LD = [&](int kc, s8* A, s8* Bv) {
    int kk = kc * 32 + kseg;
#pragma unroll
    for (int i = 0; i < 4; ++i) A[i] = *(const s8*)(h2flat + (size_t)arow[i] * H_ + kk);
#pragma unroll
    for (int j = 0; j < 4; ++j) Bv[j] = *(const s8*)(outWp + (size_t)bcolv[j] * H_ + kk);
  };
  LD(0, a, b);
  for (int c = 0; c < 32; ++c) {
    if (c + 1 < 32) LD(c + 1, an, bn);
#pragma unroll
    for (int i = 0; i < 4; ++i)
#pragma unroll
      for (int j = 0; j < 4; ++j) acc[i][j] = mfma16(a[i], b[j], acc[i][j]);
#pragma unroll
    for (int i = 0; i < 4; ++i) a[i] = an[i];
#pragma unroll
    for (int j = 0; j < 4; ++j) b[j] = bn[j];
  }

#pragma unroll
  for (int i = 0; i < 4; ++i)
#pragma unroll
    for (int j = 0; j < 4; ++j)
#pragma unroll
      for (int r = 0; r < 4; ++r)
        lg[wr + i * 16 + quad * 4 + r][wc + j * 16 + l15] = acc[i][j][r] + outB[bcolv[j]];
  __syncthreads();

  // dual softmax + CE: 2 threads per row (mel: cols 0..47, har: 48..127)
  const int row = tid >> 1, half = tid & 1;
  const int cbeg = half ? 48 : 0, cend = half ? 128 : 48;
  float m = -1e30f;
  for (int c = cbeg; c < cend; ++c) m = fmaxf(m, lg[row][c]);
  float s = 0.f;
  for (int c = cbeg; c < cend; ++c) s += __expf(lg[row][c] - m);
  float rinv = 1.f / s;
  float* orow = out + (size_t)(r0 + row) * D_;
  for (int c = cbeg; c < cend; ++c) orow[c] = __expf(lg[row][c] - m) * rinv;

  int tg = targets[(size_t)(r0 + row) * 2 + half];
  int tc = half ? (48 + tg) : tg;
  float ce = -(lg[row][tc] - m - logf(s));
  red2[tid] = 0.5f * ce;
  __syncthreads();
  for (int o = 128; o > 0; o >>= 1) {
    if (tid < o) red2[tid] += red2[tid + o];
    __syncthreads();
  }
  if (tid == 0) atomicAdd(loss, red2[0]);
}

__global__ void finalize_loss(const float* __restrict__ loss, float* __restrict__ out)
{
  out[(size_t)T_ * B_ * D_] = loss[0] * (1.f / (float)(T_ * B_));
}

// ---------------------------------------------------------------------------
extern "C" void kernel_launch(void* const* d_in, const int* in_sizes, int n_in,
                              void* d_out, int out_size, void* d_ws, size_t ws_size,
                              hipStream_t stream)
{
  const float* inSeq = (const float*)d_in[0];
  const int* targets = (const int*)d_in[1];
  const float* W1 = (const float*)d_in[2];
  const float* b1 = (const float*)d_in[3];
  const float* W2 = (const float*)d_in[4];
  const float* b2 = (const float*)d_in[5];
  const float* outW = (const float*)d_in[6];
  const float* outB = (const float*)d_in[7];
  float* out = (float*)d_out;

  // workspace layout (~104 MB total)
  char* w = (char*)d_ws;
  auto alloc = [&](size_t bytes) {
    char* r = w;
    w += (bytes + 255) & ~(size_t)255;
    return r;
  };
  unsigned short* W1p = (unsigned short*)alloc((size_t)4096 * K1_ * 2);
  unsigned short* W2p = (unsigned short*)alloc((size_t)4096 * K2_ * 2);
  unsigned short* xbf = (unsigned short*)alloc((size_t)T_ * B_ * D_ * 2);
  unsigned short* h1b = (unsigned short*)alloc((size_t)2 * B_ * H_ * 2);
  unsigned short* h2all = (unsigned short*)alloc((size_t)(T_ + 1) * B_ * H_ * 2);
  float* c1 = (float*)alloc((size_t)B_ * H_ * 4);
  float* c2 = (float*)alloc((size_t)B_ * H_ * 4);
  unsigned short* outWp = (unsigned short*)alloc((size_t)H_ * D_ * 2);
  float* loss = (float*)alloc(256);

  prep_misc<<<dim3((T_ * B_ * D_) / 256), dim3(256), 0, stream>>>(
      inSeq, outW, xbf, outWp, h1b, h2all, c1, c2, loss);
  pack_w<<<dim3(K1_ / 64, 16, 4), dim3(256), 0, stream>>>(W1, W1p, K1_);
  pack_w<<<dim3(K2_ / 64, 16, 4), dim3(256), 0, stream>>>(W2, W2p, K2_);

  for (int p = 0; p <= T_; ++p)
    phase_kernel<<<dim3(512), dim3(256), 0, stream>>>(
        p, xbf, W1p, W2p, b1, b2, h1b, h2all, c1, c2);

  proj_kernel<<<dim3(256), dim3(256), 0, stream>>>(
      h2all + (size_t)B_ * H_, outWp, outB, targets, out, loss);
  finalize_loss<<<dim3(1), dim3(1), 0, stream>>>(loss, out);
}